// Round 1
// baseline (7537.709 us; speedup 1.0000x reference)
//
#include <hip/hip_runtime.h>

#define NB 64      // batch
#define NS 512     // seq len
#define NE 512     // emb dim
#define NH 512     // per-dir hidden
#define NG 2048    // 4*NH
#define NT 64      // tags
#define KC 1024    // combined K = NE + NH
#define HB 16777216  // NS*NB*NH elements (per-direction h_all span)
#define NEGV (-10000.0f)

typedef __attribute__((ext_vector_type(8))) short bf16x8;
typedef __attribute__((ext_vector_type(4))) float f32x4;
typedef unsigned short u16;

__device__ __forceinline__ u16 f2bf(float x) {
    unsigned u = __builtin_bit_cast(unsigned, x);
    u += 0x7fffu + ((u >> 16) & 1u);
    return (u16)(u >> 16);
}
__device__ __forceinline__ float sig_(float x) { return 1.0f / (1.0f + expf(-x)); }

// ---------- prep: combined [W_ih | W_hh] -> bf16, [2][2048][1024] ----------
__global__ void prep_wcomb(const float* __restrict__ wihf, const float* __restrict__ whhf,
                           const float* __restrict__ wihb, const float* __restrict__ whhb,
                           u16* __restrict__ wcomb) {
    int idx = blockIdx.x * 256 + threadIdx.x;   // 1,048,576 threads, 4 elems each
    int base = idx * 4;
    int d = base >> 21;
    int rem = base & ((1 << 21) - 1);
    int n = rem >> 10;
    int k = rem & 1023;
    const float* wih = d ? wihb : wihf;
    const float* whh = d ? whhb : whhf;
    const float* src = (k < NE) ? (wih + n * NE + k) : (whh + n * NH + (k - NE));
    float4 v = *reinterpret_cast<const float4*>(src);
    ushort4 o;
    o.x = f2bf(v.x); o.y = f2bf(v.y); o.z = f2bf(v.z); o.w = f2bf(v.w);
    *reinterpret_cast<ushort4*>(wcomb + base) = o;
}

// ---------- prep: w_out->bf16, bias = b_ih+b_hh, zero_h, c_state=0 ----------
__global__ void prep_misc(const float* __restrict__ wout,
                          const float* __restrict__ bihf, const float* __restrict__ bhhf,
                          const float* __restrict__ bihb, const float* __restrict__ bhhb,
                          u16* __restrict__ woutbf, float* __restrict__ bias,
                          u16* __restrict__ zeroh, float* __restrict__ cst) {
    int idx = blockIdx.x * 256 + threadIdx.x;   // 167,936 threads exactly
    if (idx < 65536) { woutbf[idx] = f2bf(wout[idx]); return; }
    idx -= 65536;
    if (idx < 4096) {
        int d = idx >> 11, g = idx & 2047;
        bias[idx] = d ? (bihb[g] + bhhb[g]) : (bihf[g] + bhhf[g]);
        return;
    }
    idx -= 4096;
    if (idx < 32768) { zeroh[idx] = 0; return; }
    idx -= 32768;
    cst[idx] = 0.0f;
}

// ---------- prep: embedding gather -> x_bf[(s*64+b)][512] bf16 ----------
__global__ void prep_embed(const float* __restrict__ emb, const int* __restrict__ sents,
                           u16* __restrict__ xbf) {
    int idx = blockIdx.x * 256 + threadIdx.x;   // 4,194,304 threads, 4 elems each
    int m = idx >> 7;
    int e = (idx & 127) << 2;
    int s = m >> 6, b = m & 63;
    int tok = sents[b * NS + s];
    float4 v = *reinterpret_cast<const float4*>(emb + (size_t)tok * NE + e);
    ushort4 o;
    o.x = f2bf(v.x); o.y = f2bf(v.y); o.z = f2bf(v.z); o.w = f2bf(v.w);
    *reinterpret_cast<ushort4*>(xbf + (size_t)m * NE + e) = o;
}

// ---------- one LSTM time step, both directions. grid (64 jblk, 2 dir), 256 thr ----------
__global__ void lstm_step(const u16* __restrict__ xbf, const u16* __restrict__ wcomb,
                          const float* __restrict__ bias, const u16* __restrict__ zeroh,
                          float* __restrict__ cst, u16* __restrict__ hall, int step) {
    const int jblk = blockIdx.x;   // 0..63 -> j slice of 8
    const int dir = blockIdx.y;    // 0 fwd, 1 bwd
    const int s = dir ? (NS - 1 - step) : step;
    const u16* hprev = (step == 0) ? zeroh
                                   : (hall + (size_t)dir * HB + (size_t)(dir ? s + 1 : s - 1) * (NB * NH));
    const int t = threadIdx.x;
    const int w = t >> 6, l = t & 63;
    const int l16 = l & 15, lhi = l >> 4;

    // A row = batch (w*16 + l16); B rows = gate rows for n_local = l16 and 16+l16
    const u16* xrow = xbf + (size_t)(s * NB + w * 16 + l16) * NE;
    const u16* hrow = hprev + (size_t)(w * 16 + l16) * NH;
    const int n0 = l16, n1 = 16 + l16;
    const int gr0 = (n0 >> 3) * NH + jblk * 8 + (n0 & 7);
    const int gr1 = (n1 >> 3) * NH + jblk * 8 + (n1 & 7);
    const u16* b0row = wcomb + (size_t)(dir * NG + gr0) * KC;
    const u16* b1row = wcomb + (size_t)(dir * NG + gr1) * KC;

    f32x4 acc0 = {0.f, 0.f, 0.f, 0.f};
    f32x4 acc1 = {0.f, 0.f, 0.f, 0.f};
#pragma unroll
    for (int kt = 0; kt < 16; ++kt) {             // x part, k in [0,512)
        int k = kt * 32 + lhi * 8;
        bf16x8 a  = *reinterpret_cast<const bf16x8*>(xrow + k);
        bf16x8 b0 = *reinterpret_cast<const bf16x8*>(b0row + k);
        bf16x8 b1 = *reinterpret_cast<const bf16x8*>(b1row + k);
        acc0 = __builtin_amdgcn_mfma_f32_16x16x32_bf16(a, b0, acc0, 0, 0, 0);
        acc1 = __builtin_amdgcn_mfma_f32_16x16x32_bf16(a, b1, acc1, 0, 0, 0);
    }
#pragma unroll
    for (int kt = 0; kt < 16; ++kt) {             // h part, k in [512,1024)
        int k = kt * 32 + lhi * 8;
        bf16x8 a  = *reinterpret_cast<const bf16x8*>(hrow + k);
        bf16x8 b0 = *reinterpret_cast<const bf16x8*>(b0row + NE + k);
        bf16x8 b1 = *reinterpret_cast<const bf16x8*>(b1row + NE + k);
        acc0 = __builtin_amdgcn_mfma_f32_16x16x32_bf16(a, b0, acc0, 0, 0, 0);
        acc1 = __builtin_amdgcn_mfma_f32_16x16x32_bf16(a, b1, acc1, 0, 0, 0);
    }

    __shared__ float gates[NB][33];
    const float* bs = bias + dir * NG;
#pragma unroll
    for (int r = 0; r < 4; ++r) {
        int bb = w * 16 + lhi * 4 + r;            // D row -> batch
        gates[bb][n0] = acc0[r] + bs[gr0];
        gates[bb][n1] = acc1[r] + bs[gr1];
    }
    __syncthreads();

#pragma unroll
    for (int pair = 0; pair < 2; ++pair) {
        int p = t + pair * 256;                   // 512 (b,jj) pairs
        int bb = p >> 3, jj = p & 7;
        float gi = gates[bb][jj];
        float gf = gates[bb][8 + jj];
        float gg = gates[bb][16 + jj];
        float go = gates[bb][24 + jj];
        int j = jblk * 8 + jj;
        size_t coff = (size_t)(dir * NB + bb) * NH + j;
        float c = cst[coff];
        float cn = sig_(gf) * c + sig_(gi) * tanhf(gg);
        float h = sig_(go) * tanhf(cn);
        cst[coff] = cn;
        hall[(size_t)dir * HB + (size_t)(s * NB + bb) * NH + j] = f2bf(h);
    }
}

// ---------- emissions: [s*64+b][64] = concat(h_f,h_b) @ w_out^T + b_out ----------
__global__ void emis_kernel(const u16* __restrict__ hall, const u16* __restrict__ woutbf,
                            const float* __restrict__ bout, float* __restrict__ emis) {
    const int blk = blockIdx.x;                   // 512 blocks, 64 rows each
    const int t = threadIdx.x;
    const int w = t >> 6, l = t & 63;
    const int l16 = l & 15, lhi = l >> 4;

    const u16* arow0 = hall + (size_t)(blk * 64 + w * 16 + l16) * NH;
    const u16* arow1 = arow0 + HB;
    const u16* br0 = woutbf + (size_t)(0 * 16 + l16) * KC;
    const u16* br1 = woutbf + (size_t)(1 * 16 + l16) * KC;
    const u16* br2 = woutbf + (size_t)(2 * 16 + l16) * KC;
    const u16* br3 = woutbf + (size_t)(3 * 16 + l16) * KC;

    f32x4 a0 = {0.f,0.f,0.f,0.f}, a1 = {0.f,0.f,0.f,0.f}, a2 = {0.f,0.f,0.f,0.f}, a3 = {0.f,0.f,0.f,0.f};
#pragma unroll
    for (int kt = 0; kt < 16; ++kt) {             // h_f part
        int k = kt * 32 + lhi * 8;
        bf16x8 a = *reinterpret_cast<const bf16x8*>(arow0 + k);
        a0 = __builtin_amdgcn_mfma_f32_16x16x32_bf16(a, *reinterpret_cast<const bf16x8*>(br0 + k), a0, 0, 0, 0);
        a1 = __builtin_amdgcn_mfma_f32_16x16x32_bf16(a, *reinterpret_cast<const bf16x8*>(br1 + k), a1, 0, 0, 0);
        a2 = __builtin_amdgcn_mfma_f32_16x16x32_bf16(a, *reinterpret_cast<const bf16x8*>(br2 + k), a2, 0, 0, 0);
        a3 = __builtin_amdgcn_mfma_f32_16x16x32_bf16(a, *reinterpret_cast<const bf16x8*>(br3 + k), a3, 0, 0, 0);
    }
#pragma unroll
    for (int kt = 0; kt < 16; ++kt) {             // h_b part
        int k = kt * 32 + lhi * 8;
        bf16x8 a = *reinterpret_cast<const bf16x8*>(arow1 + k);
        a0 = __builtin_amdgcn_mfma_f32_16x16x32_bf16(a, *reinterpret_cast<const bf16x8*>(br0 + NH + k), a0, 0, 0, 0);
        a1 = __builtin_amdgcn_mfma_f32_16x16x32_bf16(a, *reinterpret_cast<const bf16x8*>(br1 + NH + k), a1, 0, 0, 0);
        a2 = __builtin_amdgcn_mfma_f32_16x16x32_bf16(a, *reinterpret_cast<const bf16x8*>(br2 + NH + k), a2, 0, 0, 0);
        a3 = __builtin_amdgcn_mfma_f32_16x16x32_bf16(a, *reinterpret_cast<const bf16x8*>(br3 + NH + k), a3, 0, 0, 0);
    }
#pragma unroll
    for (int r = 0; r < 4; ++r) {
        int gm = blk * 64 + w * 16 + lhi * 4 + r;
        emis[(size_t)gm * NT + 0 * 16 + l16] = a0[r] + bout[0 * 16 + l16];
        emis[(size_t)gm * NT + 1 * 16 + l16] = a1[r] + bout[1 * 16 + l16];
        emis[(size_t)gm * NT + 2 * 16 + l16] = a2[r] + bout[2 * 16 + l16];
        emis[(size_t)gm * NT + 3 * 16 + l16] = a3[r] + bout[3 * 16 + l16];
    }
}

// ---------- gold score per batch ----------
__global__ void gold_kernel(const float* __restrict__ emis, const int* __restrict__ tags,
                            const float* __restrict__ trans, float* __restrict__ gold) {
    int b = blockIdx.x, t = threadIdx.x;
    float acc = 0.f;
    for (int s = t; s < NS; s += 256) {
        int tag = tags[b * NS + s];
        int prev = (s == 0) ? 0 : tags[b * NS + s - 1];
        acc += emis[(size_t)(s * NB + b) * NT + tag] + trans[tag * NT + prev];
    }
    acc += __shfl_xor(acc, 1);  acc += __shfl_xor(acc, 2);  acc += __shfl_xor(acc, 4);
    acc += __shfl_xor(acc, 8);  acc += __shfl_xor(acc, 16); acc += __shfl_xor(acc, 32);
    __shared__ float red[4];
    if ((t & 63) == 0) red[t >> 6] = acc;
    __syncthreads();
    if (t == 0) gold[b] = red[0] + red[1] + red[2] + red[3];
}

// ---------- CRF forward (log partition) per batch ----------
__global__ void crf_kernel(const float* __restrict__ emis, const float* __restrict__ trans,
                           float* __restrict__ fwd) {
    int b = blockIdx.x, t = threadIdx.x;
    __shared__ float transT[64][65];   // [prev][next]
    __shared__ float alA[64], alB[64];
    for (int idx = t; idx < 4096; idx += 256) {
        int next = idx & 63, prev = idx >> 6;
        transT[prev][next] = trans[next * NT + prev];
    }
    if (t < 64) alA[t] = (t == 0) ? 0.f : NEGV;
    __syncthreads();

    int next = t >> 2, q = t & 3;
    float* cur = alA;
    float* nxt = alB;
    for (int s = 0; s < NS; ++s) {
        float emit = emis[(size_t)(s * NB + b) * NT + next];
        int p0 = q * 16;
        float M = -3.0e38f;
#pragma unroll
        for (int i = 0; i < 16; ++i) {
            float v = cur[p0 + i] + transT[p0 + i][next];
            M = fmaxf(M, v);
        }
        M = fmaxf(M, __shfl_xor(M, 1));
        M = fmaxf(M, __shfl_xor(M, 2));
        float Ssum = 0.f;
#pragma unroll
        for (int i = 0; i < 16; ++i) {
            float v = cur[p0 + i] + transT[p0 + i][next];
            Ssum += expf(v - M);
        }
        Ssum += __shfl_xor(Ssum, 1);
        Ssum += __shfl_xor(Ssum, 2);
        if (q == 0) nxt[next] = M + logf(Ssum) + emit;
        __syncthreads();
        float* tmp = cur; cur = nxt; nxt = tmp;
    }
    if (t < 64) {
        float v = cur[t];
        float M = v;
        for (int d = 1; d < 64; d <<= 1) M = fmaxf(M, __shfl_xor(M, d));
        float e = expf(v - M);
        for (int d = 1; d < 64; d <<= 1) e += __shfl_xor(e, d);
        if (t == 0) fwd[b] = M + logf(e);
    }
}

// ---------- final: mean(fwd - gold) ----------
__global__ void final_kernel(const float* __restrict__ fwd, const float* __restrict__ gold,
                             float* __restrict__ out) {
    int t = threadIdx.x;   // 64
    float v = fwd[t] - gold[t];
    for (int d = 1; d < 64; d <<= 1) v += __shfl_xor(v, d);
    if (t == 0) out[0] = v * (1.0f / 64.0f);
}

extern "C" void kernel_launch(void* const* d_in, const int* in_sizes, int n_in,
                              void* d_out, int out_size, void* d_ws, size_t ws_size,
                              hipStream_t stream) {
    (void)in_sizes; (void)n_in; (void)out_size; (void)ws_size;
    const int* sents = (const int*)d_in[0];
    const int* tags  = (const int*)d_in[1];
    const float* emb  = (const float*)d_in[3];
    const float* wihf = (const float*)d_in[4];
    const float* whhf = (const float*)d_in[5];
    const float* bihf = (const float*)d_in[6];
    const float* bhhf = (const float*)d_in[7];
    const float* wihb = (const float*)d_in[8];
    const float* whhb = (const float*)d_in[9];
    const float* bihb = (const float*)d_in[10];
    const float* bhhb = (const float*)d_in[11];
    const float* wout = (const float*)d_in[12];
    const float* bout = (const float*)d_in[13];
    const float* trans = (const float*)d_in[14];

    char* ws = (char*)d_ws;
    u16*   WCOMB  = (u16*)(ws + 0);              //  8 MiB  [2][2048][1024] bf16
    u16*   WOUTBF = (u16*)(ws + 8388608);        //  128 KiB [64][1024] bf16
    float* BIAS   = (float*)(ws + 8519680);      //  16 KiB  [2][2048] f32
    u16*   ZEROH  = (u16*)(ws + 8536064);        //  64 KiB  [64][512] bf16
    float* CST    = (float*)(ws + 8601600);      //  256 KiB [2][64][512] f32
    u16*   XBF    = (u16*)(ws + 8863744);        //  32 MiB  [32768][512] bf16
    u16*   HALL   = (u16*)(ws + 42418176);       //  64 MiB  [2][512][64][512] bf16
    float* EMIS   = (float*)(ws + 109527040);    //  8 MiB   [512*64][64] f32
    float* FWD    = (float*)(ws + 117915648);    //  [64] f32
    float* GOLD   = (float*)(ws + 117915904);    //  [64] f32

    prep_wcomb<<<4096, 256, 0, stream>>>(wihf, whhf, wihb, whhb, WCOMB);
    prep_misc<<<656, 256, 0, stream>>>(wout, bihf, bhhf, bihb, bhhb, WOUTBF, BIAS, ZEROH, CST);
    prep_embed<<<16384, 256, 0, stream>>>(emb, sents, XBF);

    for (int step = 0; step < NS; ++step) {
        lstm_step<<<dim3(64, 2), 256, 0, stream>>>(XBF, WCOMB, BIAS, ZEROH, CST, HALL, step);
    }

    emis_kernel<<<512, 256, 0, stream>>>(HALL, WOUTBF, bout, EMIS);
    gold_kernel<<<64, 256, 0, stream>>>(EMIS, tags, trans, GOLD);
    crf_kernel<<<64, 256, 0, stream>>>(EMIS, trans, FWD);
    final_kernel<<<1, 64, 0, stream>>>(FWD, GOLD, (float*)d_out);
}